// Round 1
// baseline (170.996 us; speedup 1.0000x reference)
//
#include <hip/hip_runtime.h>

#define EPSF 1e-20f

constexpr int B_ = 2, C_ = 32, O_ = 32, H_ = 256, W_ = 512;
constexpr int KS = 3;
constexpr int HO = H_ - KS + 1;   // 254
constexpr int WO = W_ - KS + 1;   // 510
constexpr int WT = 64;            // pixels per block in K2
constexpr long IMG  = (long)B_ * C_ * H_ * W_;   // 8,388,608 elements
constexpr long OUT1 = (long)B_ * O_ * HO * WO;   // 8,290,560 elements (per output)

__device__ __forceinline__ float sp_(float x) { return log1pf(expf(x)); }

// ---------------------------------------------------------------------------
// Setup: softplus all learned weights + reductions, into params buffer.
// Layout (floats): [0]=w  [1]=sum(sw)  [2]=sum(cw)  [16..304)=sw(288)
//                  [304..1328)=cw(1024)
// ---------------------------------------------------------------------------
__global__ __launch_bounds__(256) void k_setup(const float* __restrict__ w_prop,
                                               const float* __restrict__ spw,
                                               const float* __restrict__ chw,
                                               float* __restrict__ params) {
  __shared__ float red[256];
  int t = threadIdx.x;
  float l1 = 0.f;
  for (int i = t; i < 288; i += 256) { float v = sp_(spw[i]); params[16 + i] = v; l1 += v; }
  red[t] = l1; __syncthreads();
  for (int k = 128; k > 0; k >>= 1) { if (t < k) red[t] += red[t + k]; __syncthreads(); }
  float SW = red[0]; __syncthreads();
  float l2 = 0.f;
  for (int i = t; i < 1024; i += 256) { float v = sp_(chw[i]); params[304 + i] = v; l2 += v; }
  red[t] = l2; __syncthreads();
  for (int k = 128; k > 0; k >>= 1) { if (t < k) red[t] += red[t + k]; __syncthreads(); }
  if (t == 0) { params[0] = sp_(w_prop[0]); params[1] = SW; params[2] = red[0]; }
}

// ---------------------------------------------------------------------------
// K1: per-pixel vertical fusion -> gy_f, cgy_f  (float4 vectorized, rolls
// along h only so all loads stay contiguous in w)
// ---------------------------------------------------------------------------
__global__ __launch_bounds__(256) void k1_gyf(const float* __restrict__ d,
                                              const float* __restrict__ cd,
                                              const float* __restrict__ s,
                                              const float* __restrict__ gy,
                                              const float* __restrict__ cgy,
                                              const float* __restrict__ params,
                                              float* __restrict__ gy_f,
                                              float* __restrict__ cgy_f) {
  const float w = params[0];
  const float inv_w1 = 1.0f / (w + 1.0f);
  int idx = blockIdx.x * blockDim.x + threadIdx.x;
  const int n4 = (int)(IMG / 4);
  if (idx >= n4) return;
  long i4 = (long)idx * 4;
  int h = (int)((i4 >> 9) & (H_ - 1));  // W=512 -> >>9 ; H=256 -> &255
  long up = (h == 0)      ? i4 + (long)(H_ - 1) * W_ : i4 - W_;
  long dn = (h == H_ - 1) ? i4 - (long)(H_ - 1) * W_ : i4 + W_;

  float4 dv  = *(const float4*)(d + i4);
  float4 duv = *(const float4*)(d + up);
  float4 ddv = *(const float4*)(d + dn);
  float4 sv  = *(const float4*)(s + i4);
  float4 suv = *(const float4*)(s + up);
  float4 sdv = *(const float4*)(s + dn);
  float4 cduv = (h == 0)      ? make_float4(0.f, 0.f, 0.f, 0.f) : *(const float4*)(cd + up);
  float4 cddv = (h == H_ - 1) ? make_float4(0.f, 0.f, 0.f, 0.f) : *(const float4*)(cd + dn);
  float4 gyv  = *(const float4*)(gy + i4);
  float4 cgyv = *(const float4*)(cgy + i4);

  const float* pdu = (const float*)&duv;  const float* pdd = (const float*)&ddv;
  const float* ps  = (const float*)&sv;   const float* psu = (const float*)&suv;
  const float* psd = (const float*)&sdv;  const float* pcu = (const float*)&cduv;
  const float* pcd = (const float*)&cddv; const float* pg  = (const float*)&gyv;
  const float* pc  = (const float*)&cgyv;

  float og[4], oc[4];
#pragma unroll
  for (int j = 0; j < 4; ++j) {
    float cu = pcu[j], cdn = pcd[j];
    float cfd = ps[j] * psu[j] * psd[j] * cu * cu;         // cd_up twice (faithful)
    float height = (cu * pdu[j] + cdn * pdd[j]) / (cu + cdn + EPSF);
    float gfd = (pdd[j] - pdu[j]) * 0.5f / (height + EPSF);
    float a = w * pc[j];
    og[j] = (a * pg[j] + cfd * gfd) / (a + cfd + EPSF);
    oc[j] = (a + cfd) * inv_w1;
  }
  *(float4*)(gy_f + i4)  = make_float4(og[0], og[1], og[2], og[3]);
  *(float4*)(cgy_f + i4) = make_float4(oc[0], oc[1], oc[2], oc[3]);
}

// ---------------------------------------------------------------------------
// K2: fused 3x3 grouped conv (stage 2) + 1x1 channel mix (stage 3).
// Block = 256 threads handling one (b, ho, 64-wide wo tile).
// Phase A: 32 channels x 64 pixels of {gy_sp*cgy_sp, cgy_sp} -> LDS.
// Phase B: per-pixel 32->32 channel mix from registers -> both outputs.
// ---------------------------------------------------------------------------
__global__ __launch_bounds__(256) void k2_fused(const float* __restrict__ gy_f,
                                                const float* __restrict__ cgy_f,
                                                const float* __restrict__ spr,
                                                const float* __restrict__ params,
                                                const float* __restrict__ bias,
                                                float* __restrict__ out) {
  __shared__ float As[C_][WT];
  __shared__ float Bs[C_][WT];
  __shared__ float sw_s[288];
  __shared__ float cw_s[1024];
  __shared__ float bias_s[O_];

  const int b = blockIdx.z;
  const int ho = blockIdx.y;
  const int wo0 = blockIdx.x * WT;
  const int t = threadIdx.x;

  for (int i = t; i < 288; i += 256) sw_s[i] = params[16 + i];
  for (int i = t; i < 1024; i += 256) cw_s[i] = params[304 + i];
  if (t < O_) bias_s[t] = bias[t];
  const float SW = params[1];
  const float CWsum = params[2];
  __syncthreads();

  const int p = t & (WT - 1);
  const int grp = t >> 6;  // 0..3
  const int wo = wo0 + p;
  const bool valid = (wo < WO);

  // ---- Phase A ----
  for (int c = grp; c < C_; c += 4) {
    float gy_sp = 0.f, cgy_sp = 0.f;
    if (valid) {
      const long base = ((long)(b * C_ + c) * H_ + ho) * W_ + wo;
      const float* gf = gy_f + base;
      const float* cf = cgy_f + base;
      const float* sp = spr + (long)(b * C_ + c) * 9 * HO * WO + (long)ho * WO + wo;
      float nom = 0.f, den = 0.f;
#pragma unroll
      for (int i = 0; i < 3; ++i) {
#pragma unroll
        for (int j = 0; j < 3; ++j) {
          float g   = gf[i * W_ + j];
          float cg  = cf[i * W_ + j];
          float spv = sp[(long)(i * 3 + j) * HO * WO];
          float swv = sw_s[c * 9 + i * 3 + j];
          float cp = cg * spv * swv;
          nom += cp * g;
          den += cp;
        }
      }
      gy_sp = nom / (den + EPSF);
      cgy_sp = den / SW;
    }
    As[c][p] = gy_sp * cgy_sp;
    Bs[c][p] = cgy_sp;
  }
  __syncthreads();

  // ---- Phase B ----
  if (!valid) return;
  float a_reg[C_], b_reg[C_];
#pragma unroll
  for (int c = 0; c < C_; ++c) { a_reg[c] = As[c][p]; b_reg[c] = Bs[c][p]; }

  for (int o = grp; o < O_; o += 4) {
    float n2 = 0.f, d2 = 0.f;
#pragma unroll
    for (int c = 0; c < C_; ++c) {
      float wv = cw_s[o * C_ + c];
      n2 += a_reg[c] * wv;
      d2 += b_reg[c] * wv;
    }
    long oidx = ((long)(b * O_ + o) * HO + ho) * WO + wo;
    out[oidx]        = n2 / (d2 + EPSF) + bias_s[o];
    out[OUT1 + oidx] = d2 / CWsum;
  }
}

// ---------------------------------------------------------------------------
extern "C" void kernel_launch(void* const* d_in, const int* in_sizes, int n_in,
                              void* d_out, int out_size, void* d_ws, size_t ws_size,
                              hipStream_t stream) {
  const float* d      = (const float*)d_in[0];
  const float* cd     = (const float*)d_in[1];
  const float* s      = (const float*)d_in[2];
  // d_in[3]=cs, d_in[4]=gx, d_in[5]=cgx are unused by the reference
  const float* gy     = (const float*)d_in[6];
  const float* cgy    = (const float*)d_in[7];
  const float* spr    = (const float*)d_in[8];
  const float* w_prop = (const float*)d_in[9];
  const float* spw    = (const float*)d_in[10];
  const float* chw    = (const float*)d_in[11];
  const float* bias   = (const float*)d_in[12];
  float* out = (float*)d_out;

  float* gy_f   = (float*)d_ws;
  float* cgy_f  = gy_f + IMG;
  float* params = cgy_f + IMG;

  k_setup<<<1, 256, 0, stream>>>(w_prop, spw, chw, params);

  int n4 = (int)(IMG / 4);
  k1_gyf<<<(n4 + 255) / 256, 256, 0, stream>>>(d, cd, s, gy, cgy, params, gy_f, cgy_f);

  dim3 g2((WO + WT - 1) / WT, HO, B_);
  k2_fused<<<g2, 256, 0, stream>>>(gy_f, cgy_f, spr, params, bias, out);
}

// Round 2
// 163.838 us; speedup vs baseline: 1.0437x; 1.0437x over previous
//
#include <hip/hip_runtime.h>

#define EPSF 1e-20f

constexpr int B_ = 2, C_ = 32, O_ = 32, H_ = 256, W_ = 512;
constexpr int KS = 3;
constexpr int HO = H_ - KS + 1;   // 254
constexpr int WO = W_ - KS + 1;   // 510
constexpr int TH = 8;             // output rows per block
constexpr int WT = 32;            // output cols per block
constexpr long OUT1 = (long)B_ * O_ * HO * WO;   // elements per output tensor

__device__ __forceinline__ float sp_(float x) { return log1pf(expf(x)); }

// ---------------------------------------------------------------------------
// Setup: softplus all learned weights + reductions, into params buffer.
// Layout (floats): [0]=w  [1]=sum(sw)  [2]=sum(cw)  [16..304)=sw(288)
//                  [304..1328)=cw(1024)
// ---------------------------------------------------------------------------
__global__ __launch_bounds__(256) void k_setup(const float* __restrict__ w_prop,
                                               const float* __restrict__ spw,
                                               const float* __restrict__ chw,
                                               float* __restrict__ params) {
  __shared__ float red[256];
  int t = threadIdx.x;
  float l1 = 0.f;
  for (int i = t; i < 288; i += 256) { float v = sp_(spw[i]); params[16 + i] = v; l1 += v; }
  red[t] = l1; __syncthreads();
  for (int k = 128; k > 0; k >>= 1) { if (t < k) red[t] += red[t + k]; __syncthreads(); }
  float SW = red[0]; __syncthreads();
  float l2 = 0.f;
  for (int i = t; i < 1024; i += 256) { float v = sp_(chw[i]); params[304 + i] = v; l2 += v; }
  red[t] = l2; __syncthreads();
  for (int k = 128; k > 0; k >>= 1) { if (t < k) red[t] += red[t + k]; __syncthreads(); }
  if (t == 0) { params[0] = sp_(w_prop[0]); params[1] = SW; params[2] = red[0]; }
}

// ---------------------------------------------------------------------------
// Fully fused kernel: stage-1 vertical fusion (recomputed per-channel into a
// 10x34 LDS halo tile) + 3x3 grouped conv + 1x1 channel mix.
// Block = 256 threads = one 8x32 output tile of one batch. 1 pixel/thread,
// 64 accumulator regs (n2[32], d2[32]) carried across the channel loop.
// ---------------------------------------------------------------------------
__global__ __launch_bounds__(256) void k_fused(const float* __restrict__ d,
                                               const float* __restrict__ cd,
                                               const float* __restrict__ s,
                                               const float* __restrict__ gy,
                                               const float* __restrict__ cgy,
                                               const float* __restrict__ spr,
                                               const float* __restrict__ params,
                                               const float* __restrict__ bias,
                                               float* __restrict__ out) {
  __shared__ float gf[TH + 2][WT + 2];   // gy_f tile
  __shared__ float cf[TH + 2][WT + 2];   // cgy_f tile
  __shared__ float sw_s[288];
  __shared__ float cw_s[1024];

  const int b   = blockIdx.z;
  const int ho0 = blockIdx.y * TH;
  const int wo0 = blockIdx.x * WT;
  const int t   = threadIdx.x;

  for (int i = t; i < 288; i += 256)  sw_s[i] = params[16 + i];
  for (int i = t; i < 1024; i += 256) cw_s[i] = params[304 + i];
  const float w      = params[0];
  const float inv_w1 = 1.0f / (w + 1.0f);
  const float invSW  = 1.0f / params[1];
  const float invCW  = 1.0f / params[2];

  const int tr = t >> 5;        // 0..7
  const int tw = t & 31;        // 0..31
  const int ho = ho0 + tr;
  const int wo = wo0 + tw;
  const bool valid = (ho < HO) && (wo < WO);

  float n2[O_], d2[O_];
#pragma unroll
  for (int o = 0; o < O_; ++o) { n2[o] = 0.f; d2[o] = 0.f; }

  constexpr int NPOS = (TH + 2) * (WT + 2);  // 340 staging positions

  for (int c = 0; c < C_; ++c) {
    __syncthreads();  // previous iteration's LDS reads done
    // ---- stage gy_f / cgy_f for channel c into LDS ----
    const int cplane = (b * C_ + c) * H_ * W_;
    for (int pos = t; pos < NPOS; pos += 256) {
      const int r  = pos / (WT + 2);
      const int cc = pos - r * (WT + 2);
      const int gh = ho0 + r;         // row in full image (0..255 guaranteed < H needs guard at edge tiles)
      const int gw = wo0 + cc;
      float vg = 0.f, vc = 0.f;
      if (gh < H_ && gw < W_) {
        const int base = cplane + gh * W_ + gw;
        const int up   = (gh == 0)      ? base + (H_ - 1) * W_ : base - W_;
        const int dn   = (gh == H_ - 1) ? base - (H_ - 1) * W_ : base + W_;
        const float cu  = (gh == 0)      ? 0.f : cd[up];
        const float cdn = (gh == H_ - 1) ? 0.f : cd[dn];
        const float du = d[up], dd = d[dn];
        const float cfd    = s[base] * s[up] * s[dn] * cu * cu;  // cd_up twice (faithful)
        const float height = (cu * du + cdn * dd) / (cu + cdn + EPSF);
        const float gfd    = (dd - du) * 0.5f / (height + EPSF);
        const float a      = w * cgy[base];
        vg = (a * gy[base] + cfd * gfd) / (a + cfd + EPSF);
        vc = (a + cfd) * inv_w1;
      }
      (&gf[0][0])[pos] = vg;
      (&cf[0][0])[pos] = vc;
    }
    __syncthreads();

    // ---- consume: 3x3 patch sum for this channel + channel-mix accumulate ----
    if (valid) {
      const int sbase = (b * C_ + c) * 9 * (HO * WO) + ho * WO + wo;
      float nom = 0.f, den = 0.f;
#pragma unroll
      for (int i = 0; i < 3; ++i) {
#pragma unroll
        for (int j = 0; j < 3; ++j) {
          const float g   = gf[tr + i][tw + j];
          const float cg  = cf[tr + i][tw + j];
          const float spv = spr[sbase + (i * 3 + j) * (HO * WO)];
          const float swv = sw_s[c * 9 + i * 3 + j];
          const float cp  = cg * spv * swv;
          nom += cp * g;
          den += cp;
        }
      }
      const float gy_sp  = nom / (den + EPSF);
      const float cgy_sp = den * invSW;
      const float a      = gy_sp * cgy_sp;
#pragma unroll
      for (int o = 0; o < O_; ++o) {
        const float wv = cw_s[o * C_ + c];
        n2[o] += a * wv;
        d2[o] += cgy_sp * wv;
      }
    }
  }

  if (!valid) return;
#pragma unroll
  for (int o = 0; o < O_; ++o) {
    const int oidx = (b * O_ + o) * (HO * WO) + ho * WO + wo;
    out[oidx]        = n2[o] / (d2[o] + EPSF) + bias[o];
    out[OUT1 + oidx] = d2[o] * invCW;
  }
}

// ---------------------------------------------------------------------------
extern "C" void kernel_launch(void* const* d_in, const int* in_sizes, int n_in,
                              void* d_out, int out_size, void* d_ws, size_t ws_size,
                              hipStream_t stream) {
  const float* d      = (const float*)d_in[0];
  const float* cd     = (const float*)d_in[1];
  const float* s      = (const float*)d_in[2];
  // d_in[3]=cs, d_in[4]=gx, d_in[5]=cgx unused by the reference
  const float* gy     = (const float*)d_in[6];
  const float* cgy    = (const float*)d_in[7];
  const float* spr    = (const float*)d_in[8];
  const float* w_prop = (const float*)d_in[9];
  const float* spw    = (const float*)d_in[10];
  const float* chw    = (const float*)d_in[11];
  const float* bias   = (const float*)d_in[12];
  float* out = (float*)d_out;

  float* params = (float*)d_ws;

  k_setup<<<1, 256, 0, stream>>>(w_prop, spw, chw, params);

  dim3 g((WO + WT - 1) / WT, (HO + TH - 1) / TH, B_);  // (16, 32, 2)
  k_fused<<<g, 256, 0, stream>>>(d, cd, s, gy, cgy, spr, params, bias, out);
}